// Round 3
// baseline (343.090 us; speedup 1.0000x reference)
//
#include <hip/hip_runtime.h>
#include <stdint.h>
#include <math.h>

#define TIECAP 1024
typedef unsigned long long ull;
typedef long long ll;

struct Ctrl {
  unsigned int prefix;   // 32-bit key threshold accumulator
  int rank_rem;          // remaining 0-indexed rank within matching subset
  int tie_count;
  int done0, done1, done2, done3;
};

// Orderable-bits maps: unsigned compare == float/double ascending compare.
__device__ __forceinline__ unsigned int fkey(float f) {
  unsigned int u = __float_as_uint(f);
  return (u & 0x80000000u) ? ~u : (u | 0x80000000u);
}
__device__ __forceinline__ ull dkey(double d) {
  ull u = (ull)__double_as_longlong(d);
  return (u & 0x8000000000000000ull) ? ~u : (u | 0x8000000000000000ull);
}

__global__ void k_init(unsigned int* hist, Ctrl* ctrl, int num_rm) {
  int t = threadIdx.x;
  if (t < 1024) hist[t] = 0u;   // 4 levels x 256 bins
  if (t == 0) {
    ctrl->prefix = 0u;
    ctrl->rank_rem = num_rm - 1;  // 0-indexed rank of largest pruned key
    ctrl->tie_count = 0;
    ctrl->done0 = 0; ctrl->done1 = 0; ctrl->done2 = 0; ctrl->done3 = 0;
  }
}

// Last-block pick: scan 256 global-hist bins, find bin containing rank_rem.
// Called by every thread of the last block (needs >=256 threads).
__device__ void do_pick(unsigned int* hist, int shift, Ctrl* ctrl) {
  __shared__ unsigned int sph[256];
  __shared__ int s_r;
  int t = threadIdx.x;
  if (t == 0) s_r = ctrl->rank_rem;   // snapshot BEFORE any writer can race
  unsigned int c = 0;
  if (t < 256) { c = atomicAdd(&hist[t], 0u); sph[t] = c; }  // coherent read
  __syncthreads();
  for (int off = 1; off < 256; off <<= 1) {
    unsigned int v = 0, a = 0;
    if (t < 256) { v = sph[t]; a = (t >= off) ? sph[t - off] : 0u; }
    __syncthreads();
    if (t < 256) sph[t] = v + a;
    __syncthreads();
  }
  if (t < 256) {
    unsigned int incl = sph[t], excl = incl - c;
    unsigned int r = (unsigned int)s_r;
    if (r >= excl && r < incl) {      // exactly one thread
      ctrl->prefix |= ((unsigned int)t) << shift;
      ctrl->rank_rem = (int)(r - excl);
    }
  }
}

// keys[e] = orderable f32 image of exact f64 sum; fused level-0 hist + pick.
__global__ void k_keys(const int* __restrict__ ei, const float* __restrict__ wm,
                       int N, ll E, int D, unsigned int* __restrict__ key32,
                       unsigned int* hist, Ctrl* ctrl) {
  __shared__ unsigned int sh[256];
  __shared__ int s_last;
  int t = threadIdx.x;
  if (t < 256) sh[t] = 0u;
  __syncthreads();
  int e = blockIdx.x * 1024 + t;
  if (e < N) {
    int src = ei[e], dst = ei[E + e];
    double s = (double)wm[(ll)src * D + dst] + (double)wm[(ll)dst * D + src];
    unsigned int k = fkey((float)s);
    key32[e] = k;
    atomicAdd(&sh[k >> 24], 1u);
  }
  __syncthreads();
  if (t < 256 && sh[t]) atomicAdd(&hist[t], sh[t]);
  __threadfence();
  __syncthreads();
  if (t == 0) s_last = (atomicAdd(&ctrl->done0, 1) == (int)gridDim.x - 1) ? 1 : 0;
  __syncthreads();
  if (!s_last) return;
  do_pick(hist, 24, ctrl);
}

// One radix level (1..3): hist of 8-bit digit among prefix-matching keys + pick.
__global__ void k_level(const unsigned int* __restrict__ key32, int N, int level,
                        unsigned int* hist, Ctrl* ctrl, int* done) {
  __shared__ unsigned int sh[256];
  __shared__ int s_last;
  int t = threadIdx.x;
  if (t < 256) sh[t] = 0u;
  __syncthreads();
  unsigned int prefix = ctrl->prefix;   // written by previous kernel
  int shift = 24 - 8 * level;
  int e = blockIdx.x * 1024 + t;
  if (e < N) {
    unsigned int k = key32[e];
    if (((k ^ prefix) >> (shift + 8)) == 0u)
      atomicAdd(&sh[(k >> shift) & 0xFFu], 1u);
  }
  __syncthreads();
  if (t < 256 && sh[t]) atomicAdd(&hist[t], sh[t]);
  __threadfence();
  __syncthreads();
  if (t == 0) s_last = (atomicAdd(done, 1) == (int)gridDim.x - 1) ? 1 : 0;
  __syncthreads();
  if (!s_last) return;
  do_pick(hist, shift, ctrl);
}

// Collect the (tiny) group of elements whose 32-bit key == T, with exact f64 keys.
__global__ void k_ties(const unsigned int* __restrict__ key32,
                       const int* __restrict__ ei, const float* __restrict__ wm,
                       int N, ll E, int D, Ctrl* ctrl,
                       int* __restrict__ tieIdx, ull* __restrict__ tieKey) {
  int e = blockIdx.x * blockDim.x + threadIdx.x;
  if (e >= N) return;
  if (key32[e] == ctrl->prefix) {
    int p = atomicAdd(&ctrl->tie_count, 1);
    if (p < TIECAP) {
      int src = ei[e], dst = ei[E + e];
      double s = (double)wm[(ll)src * D + dst] + (double)wm[(ll)dst * D + src];
      tieIdx[p] = e;
      tieKey[p] = dkey(s);
    }
  }
}

// Kept iff key > T, or key == T and (f64,idx)-rank within tie group >= j.
__device__ __forceinline__ bool is_kept(unsigned int k, int e, unsigned int T,
                                        int j, int tc,
                                        const int* __restrict__ tieIdx,
                                        const ull* __restrict__ tieKey,
                                        const int* __restrict__ ei,
                                        const float* __restrict__ wm, ll E, int D) {
  if (k < T) return false;
  if (k > T) return true;
  if (j <= 0) return true;
  if (tc > TIECAP) tc = TIECAP;
  int src = ei[e], dst = ei[E + e];
  ull me = dkey((double)wm[(ll)src * D + dst] + (double)wm[(ll)dst * D + src]);
  int rank = 0;
  for (int i = 0; i < tc; ++i) {
    ull o = tieKey[i];
    rank += (o < me || (o == me && tieIdx[i] < e)) ? 1 : 0;
  }
  return rank >= j;
}

// Per-block exclusive scan of kept flags; pos packs (excl<<1)|kept; mask output.
__global__ void k_scanA(const unsigned int* __restrict__ key32, int N,
                        const Ctrl* __restrict__ ctrl,
                        const int* __restrict__ tieIdx, const ull* __restrict__ tieKey,
                        const int* __restrict__ ei, const float* __restrict__ wm,
                        ll E, int D, int* __restrict__ pos,
                        int* __restrict__ blockSums, float* __restrict__ mask_out) {
  __shared__ int sh[1024];
  unsigned int T = ctrl->prefix;
  int j = ctrl->rank_rem + 1;
  int tc = ctrl->tie_count;
  int e = blockIdx.x * 1024 + threadIdx.x;
  int m = 0;
  if (e < N) m = is_kept(key32[e], e, T, j, tc, tieIdx, tieKey, ei, wm, E, D) ? 1 : 0;
  sh[threadIdx.x] = m;
  __syncthreads();
  for (int off = 1; off < 1024; off <<= 1) {
    int v = sh[threadIdx.x];
    int add = (threadIdx.x >= (unsigned)off) ? sh[threadIdx.x - off] : 0;
    __syncthreads();
    sh[threadIdx.x] = v + add;
    __syncthreads();
  }
  if (e < N) {
    pos[e] = ((sh[threadIdx.x] - m) << 1) | m;
    mask_out[e] = m ? 1.0f : 0.0f;
  }
  if (threadIdx.x == 1023) blockSums[blockIdx.x] = sh[1023];
}

// Parallel exclusive scan of <=256 block sums.
__global__ void k_scanB(int* bs, int nb) {
  __shared__ int sh[256];
  int t = threadIdx.x;
  int v = (t < nb) ? bs[t] : 0;
  sh[t] = v;
  __syncthreads();
  for (int off = 1; off < 256; off <<= 1) {
    int x = sh[t];
    int a = (t >= off) ? sh[t - off] : 0;
    __syncthreads();
    sh[t] = x + a;
    __syncthreads();
  }
  if (t < nb) bs[t] = sh[t] - v;
}

// Stream compaction: contiguous vector reads -> LDS scatter -> contiguous writes.
// grid = (N/1024, B, 3): z=row (ei0, ei1, attr), y=batch, x=1024-elem chunk.
__global__ void k_compact(const int* __restrict__ pos, const int* __restrict__ bs,
                          const int* __restrict__ ei, const float* __restrict__ attr,
                          ll E, int N, int Kkeep, ll BK, float* __restrict__ out) {
  __shared__ float lds[1024];
  __shared__ int s_cnt;
  int t = threadIdx.x;       // 256
  int blk = blockIdx.x;
  int b = blockIdx.y;
  int r = blockIdx.z;
  int q = blk * 256 + t;     // int4/float4 slot; elements 4q..4q+3
  int4 p4 = ((const int4*)pos)[q];
  ll cb = (ll)b * N;
  float4 v;
  if (r == 0) {
    int4 d = ((const int4*)(ei + cb))[q];
    v = make_float4((float)d.x, (float)d.y, (float)d.z, (float)d.w);
  } else if (r == 1) {
    int4 d = ((const int4*)(ei + E + cb))[q];
    v = make_float4((float)d.x, (float)d.y, (float)d.z, (float)d.w);
  } else {
    v = ((const float4*)(attr + cb))[q];
  }
  if (p4.x & 1) lds[p4.x >> 1] = v.x;
  if (p4.y & 1) lds[p4.y >> 1] = v.y;
  if (p4.z & 1) lds[p4.z >> 1] = v.z;
  if (p4.w & 1) lds[p4.w >> 1] = v.w;
  if (t == 255) s_cnt = (p4.w >> 1) + (p4.w & 1);
  __syncthreads();
  ll ob = (ll)r * BK + (ll)b * Kkeep + bs[blk];
  int cnt = s_cnt;
  for (int i = t; i < cnt; i += 256) out[ob + i] = lds[i];
}

extern "C" void kernel_launch(void* const* d_in, const int* in_sizes, int n_in,
                              void* d_out, int out_size, void* d_ws, size_t ws_size,
                              hipStream_t stream) {
  const int* ei = (const int*)d_in[0];
  const float* attr = (const float*)d_in[1];
  const float* wm = (const float*)d_in[3];

  int B = in_sizes[2] - 1;                          // 64
  ll E = (ll)in_sizes[0] / 2;                       // 16777216
  int e_per = (int)(E / B);                         // 262144
  int D = (int)llround(sqrt((double)in_sizes[3]));  // 4096
  int num_rm = (int)((double)e_per * 0.3);          // 78643
  int Kkeep = e_per - num_rm;                       // 183501
  ll BK = (ll)B * Kkeep;
  int nb = (e_per + 1023) / 1024;                   // 256

  char* w = (char*)d_ws;
  size_t off = 0;
  unsigned int* key32 = (unsigned int*)(w + off); off += (size_t)e_per * 4;
  int* pos = (int*)(w + off);                     off += (size_t)e_per * 4;
  unsigned int* hist = (unsigned int*)(w + off);  off += 4 * 256 * 4;
  int* blockSums = (int*)(w + off);               off += (size_t)nb * 4;
  int* tieIdx = (int*)(w + off);                  off += (size_t)TIECAP * 4;
  ull* tieKey = (ull*)(w + off);                  off += (size_t)TIECAP * 8;
  Ctrl* ctrl = (Ctrl*)(w + off);                  off += sizeof(Ctrl);
  (void)ws_size; (void)n_in; (void)out_size;

  float* out = (float*)d_out;
  float* mask_out = out + 3 * BK;

  k_init<<<dim3(1), dim3(1024), 0, stream>>>(hist, ctrl, num_rm);
  k_keys<<<dim3(nb), dim3(1024), 0, stream>>>(ei, wm, e_per, E, D, key32, hist, ctrl);
  k_level<<<dim3(nb), dim3(1024), 0, stream>>>(key32, e_per, 1, hist + 256, ctrl, &ctrl->done1);
  k_level<<<dim3(nb), dim3(1024), 0, stream>>>(key32, e_per, 2, hist + 512, ctrl, &ctrl->done2);
  k_level<<<dim3(nb), dim3(1024), 0, stream>>>(key32, e_per, 3, hist + 768, ctrl, &ctrl->done3);
  k_ties<<<dim3(nb), dim3(1024), 0, stream>>>(key32, ei, wm, e_per, E, D, ctrl, tieIdx, tieKey);
  k_scanA<<<dim3(nb), dim3(1024), 0, stream>>>(key32, e_per, ctrl, tieIdx, tieKey,
                                               ei, wm, E, D, pos, blockSums, mask_out);
  k_scanB<<<dim3(1), dim3(256), 0, stream>>>(blockSums, nb);
  k_compact<<<dim3(nb, B, 3), dim3(256), 0, stream>>>(pos, blockSums, ei, attr,
                                                      E, e_per, Kkeep, BK, out);
}

// Round 4
// 195.214 us; speedup vs baseline: 1.7575x; 1.7575x over previous
//
#include <hip/hip_runtime.h>
#include <stdint.h>
#include <math.h>

#define CAND_CAP 8192
typedef unsigned long long ull;
typedef long long ll;
typedef unsigned int uint;

struct Ctrl {
  int binsel;   // selected top-16 bin
  int r_in;     // 0-indexed rank of threshold element within candidates
  int ncand;    // candidate count (atomic)
  int pad;
  ull Tpack;    // packed (key32<<32)|idx of threshold element
};

// keys[e] = orderable-bits of f32(wm[src,dst]+wm[dst,src]); fused 16-bit global hist.
// (f64 sum rounded to f32 == the reference's f32 add, exactly.)
__global__ void k_keys(const int* __restrict__ ei, const float* __restrict__ wm,
                       int N, ll E, int D,
                       uint* __restrict__ key32, uint* __restrict__ hist) {
  int e = blockIdx.x * blockDim.x + threadIdx.x;
  if (e >= N) return;
  int src = ei[e], dst = ei[E + e];
  double s = (double)wm[(ll)src * D + dst] + (double)wm[(ll)dst * D + src];
  uint u = __float_as_uint((float)s);
  uint k = (u & 0x80000000u) ? ~u : (u | 0x80000000u);
  key32[e] = k;
  atomicAdd(&hist[k >> 16], 1u);  // no-return atomic, hides under gather latency
}

// One block, 1024 threads: scan 64K bins, find bin containing global rank r.
__global__ void k_pick0(const uint* __restrict__ hist, int r, Ctrl* ctrl) {
  __shared__ uint sh[1024];
  int t = threadIdx.x;
  uint partial = 0;
  for (int i = 0; i < 64; ++i) partial += hist[t * 64 + i];
  sh[t] = partial;
  __syncthreads();
  for (int off = 1; off < 1024; off <<= 1) {
    uint v = sh[t];
    uint a = (t >= off) ? sh[t - off] : 0u;
    __syncthreads();
    sh[t] = v + a;
    __syncthreads();
  }
  uint incl = sh[t], base = incl - partial;
  if ((uint)r >= base && (uint)r < incl) {   // exactly one thread
    uint cum = base;
    for (int i = 0; i < 64; ++i) {
      uint c = hist[t * 64 + i];
      if ((uint)r < cum + c) {
        ctrl->binsel = t * 64 + i;
        ctrl->r_in = (int)((uint)r - cum);
        break;
      }
      cum += c;
    }
  }
}

// Collect candidates whose top-16 bits match the selected bin (~400 expected).
__global__ void k_cand(const uint* __restrict__ key32, int N, Ctrl* ctrl,
                       ull* __restrict__ cand) {
  int e = blockIdx.x * blockDim.x + threadIdx.x;
  if (e >= N) return;
  uint k = key32[e];
  if ((int)(k >> 16) == ctrl->binsel) {
    int p = atomicAdd(&ctrl->ncand, 1);
    if (p < CAND_CAP) cand[p] = ((ull)k << 32) | (uint)e;
  }
}

// One block: rank candidates by packed (key,idx); threshold = rank r_in element.
__global__ void k_pick1(const ull* __restrict__ cand, Ctrl* ctrl) {
  int nc = ctrl->ncand;
  if (nc > CAND_CAP) nc = CAND_CAP;
  int r = ctrl->r_in;
  for (int o = threadIdx.x; o < nc; o += blockDim.x) {
    ull my = cand[o];
    int cnt = 0;
    for (int i = 0; i < nc; ++i) cnt += (cand[i] < my) ? 1 : 0;
    if (cnt == r) ctrl->Tpack = my;   // exactly one (packs are unique)
  }
}

__device__ __forceinline__ int keptf(uint k, int e, ull T) {
  return ((((ull)k << 32) | (uint)e) > T) ? 1 : 0;
}

// Per-chunk kept count (chunk = 1024 elems), for the global base scan.
__global__ void k_bsum(const uint* __restrict__ key32, const Ctrl* __restrict__ ctrl,
                       int* __restrict__ bs) {
  __shared__ int sh[256];
  int t = threadIdx.x, blk = blockIdx.x;
  ull T = ctrl->Tpack;
  uint4 k4 = ((const uint4*)key32)[blk * 256 + t];
  int e0 = blk * 1024 + t * 4;
  int c = keptf(k4.x, e0, T) + keptf(k4.y, e0 + 1, T) +
          keptf(k4.z, e0 + 2, T) + keptf(k4.w, e0 + 3, T);
  sh[t] = c;
  __syncthreads();
  for (int off = 128; off > 0; off >>= 1) {
    if (t < off) sh[t] += sh[t + off];
    __syncthreads();
  }
  if (t == 0) bs[blk] = sh[0];
}

// Exclusive scan of <=256 chunk counts.
__global__ void k_scanB(int* bs, int nb) {
  __shared__ int sh[256];
  int t = threadIdx.x;
  int v = (t < nb) ? bs[t] : 0;
  sh[t] = v;
  __syncthreads();
  for (int off = 1; off < 256; off <<= 1) {
    int x = sh[t];
    int a = (t >= off) ? sh[t - off] : 0;
    __syncthreads();
    sh[t] = x + a;
    __syncthreads();
  }
  if (t < nb) bs[t] = sh[t] - v;
}

// Compaction: grid (chunk, batch). Flags from key32 (L2-hot), block scan,
// predicated direct stores (monotone addresses -> L2 write-merging, no LDS staging).
__global__ void k_compact(const uint* __restrict__ key32, const int* __restrict__ bs,
                          const Ctrl* __restrict__ ctrl, const int* __restrict__ ei,
                          const float* __restrict__ attr, ll E, int N, int Kkeep,
                          ll BK, float* __restrict__ out, float* __restrict__ mask_out) {
  __shared__ int sw[256];
  int t = threadIdx.x, blk = blockIdx.x, b = blockIdx.y;
  int q = blk * 256 + t;
  ull T = ctrl->Tpack;
  uint4 k4 = ((const uint4*)key32)[q];
  // issue the three data loads before the scan barrier (independent)
  int4 d0 = ((const int4*)(ei + (ll)b * N))[q];
  int4 d1 = ((const int4*)(ei + E + (ll)b * N))[q];
  float4 d2 = ((const float4*)(attr + (ll)b * N))[q];
  int e0 = blk * 1024 + t * 4;
  int f0 = keptf(k4.x, e0, T), f1 = keptf(k4.y, e0 + 1, T);
  int f2 = keptf(k4.z, e0 + 2, T), f3 = keptf(k4.w, e0 + 3, T);
  int c = f0 + f1 + f2 + f3;
  sw[t] = c;
  __syncthreads();
  for (int off = 1; off < 256; off <<= 1) {
    int v = sw[t];
    int a = (t >= off) ? sw[t - off] : 0;
    __syncthreads();
    sw[t] = v + a;
    __syncthreads();
  }
  ll base = (ll)bs[blk] + (sw[t] - c);
  ll ob = (ll)b * Kkeep + base;
  {
    int o = 0;
    if (f0) { out[ob + o] = (float)d0.x; o++; }
    if (f1) { out[ob + o] = (float)d0.y; o++; }
    if (f2) { out[ob + o] = (float)d0.z; o++; }
    if (f3) { out[ob + o] = (float)d0.w; o++; }
  }
  {
    float* r1 = out + BK;
    int o = 0;
    if (f0) { r1[ob + o] = (float)d1.x; o++; }
    if (f1) { r1[ob + o] = (float)d1.y; o++; }
    if (f2) { r1[ob + o] = (float)d1.z; o++; }
    if (f3) { r1[ob + o] = (float)d1.w; o++; }
  }
  {
    float* r2 = out + 2 * BK;
    int o = 0;
    if (f0) { r2[ob + o] = d2.x; o++; }
    if (f1) { r2[ob + o] = d2.y; o++; }
    if (f2) { r2[ob + o] = d2.z; o++; }
    if (f3) { r2[ob + o] = d2.w; o++; }
  }
  if (b == 0)
    ((float4*)mask_out)[q] = make_float4((float)f0, (float)f1, (float)f2, (float)f3);
}

extern "C" void kernel_launch(void* const* d_in, const int* in_sizes, int n_in,
                              void* d_out, int out_size, void* d_ws, size_t ws_size,
                              hipStream_t stream) {
  const int* ei = (const int*)d_in[0];
  const float* attr = (const float*)d_in[1];
  const float* wm = (const float*)d_in[3];

  int B = in_sizes[2] - 1;                          // 64
  ll E = (ll)in_sizes[0] / 2;                       // 16777216
  int e_per = (int)(E / B);                         // 262144
  int D = (int)llround(sqrt((double)in_sizes[3]));  // 4096
  int num_rm = (int)((double)e_per * 0.3);          // 78643
  int Kkeep = e_per - num_rm;                       // 183501
  ll BK = (ll)B * Kkeep;
  int nb = (e_per + 1023) / 1024;                   // 256

  char* w = (char*)d_ws;
  size_t off = 0;
  uint* key32 = (uint*)(w + off);  off += (size_t)e_per * 4;
  uint* hist = (uint*)(w + off);   off += 65536 * 4;
  Ctrl* ctrl = (Ctrl*)(w + off);   off += 64;
  ull* cand = (ull*)(w + off);     off += (size_t)CAND_CAP * 8;
  int* bs = (int*)(w + off);       off += (size_t)nb * 4;
  (void)ws_size; (void)n_in; (void)out_size;

  float* out = (float*)d_out;
  float* mask_out = out + 3 * BK;

  hipMemsetAsync(hist, 0, 65536 * 4 + sizeof(Ctrl), stream);
  k_keys<<<dim3((e_per + 1023) / 1024), dim3(1024), 0, stream>>>(ei, wm, e_per, E, D, key32, hist);
  k_pick0<<<dim3(1), dim3(1024), 0, stream>>>(hist, num_rm - 1, ctrl);
  k_cand<<<dim3(nb), dim3(1024), 0, stream>>>(key32, e_per, ctrl, cand);
  k_pick1<<<dim3(1), dim3(1024), 0, stream>>>(cand, ctrl);
  k_bsum<<<dim3(nb), dim3(256), 0, stream>>>(key32, ctrl, bs);
  k_scanB<<<dim3(1), dim3(256), 0, stream>>>(bs, nb);
  k_compact<<<dim3(nb, B), dim3(256), 0, stream>>>(key32, bs, ctrl, ei, attr,
                                                   E, e_per, Kkeep, BK, out, mask_out);
}

// Round 5
// 182.399 us; speedup vs baseline: 1.8810x; 1.0703x over previous
//
#include <hip/hip_runtime.h>
#include <stdint.h>
#include <math.h>

#define CAND_CAP 8192
typedef unsigned long long ull;
typedef long long ll;
typedef unsigned int uint;

struct Ctrl {
  int binsel;   // selected top-16 bin
  int r_in;     // 0-indexed rank of threshold element within candidates
  int ncand;    // candidate count (atomic)
  int pad;
  ull Tpack;    // packed (key32<<32)|idx of threshold element
};

// keys[e] = orderable-bits of f32(wm[src,dst]+wm[dst,src]); fused 16-bit global hist.
__global__ void k_keys(const int* __restrict__ ei, const float* __restrict__ wm,
                       int N, ll E, int D,
                       uint* __restrict__ key32, uint* __restrict__ hist) {
  int e = blockIdx.x * blockDim.x + threadIdx.x;
  if (e >= N) return;
  int src = ei[e], dst = ei[E + e];
  double s = (double)wm[(ll)src * D + dst] + (double)wm[(ll)dst * D + src];
  uint u = __float_as_uint((float)s);
  uint k = (u & 0x80000000u) ? ~u : (u | 0x80000000u);
  key32[e] = k;
  atomicAdd(&hist[k >> 16], 1u);
}

// One block, 1024 threads: scan 64K bins, find bin containing global rank r.
__global__ void k_pick0(const uint* __restrict__ hist, int r, Ctrl* ctrl) {
  __shared__ uint sh[1024];
  int t = threadIdx.x;
  uint partial = 0;
  for (int i = 0; i < 64; ++i) partial += hist[t * 64 + i];
  sh[t] = partial;
  __syncthreads();
  for (int off = 1; off < 1024; off <<= 1) {
    uint v = sh[t];
    uint a = (t >= off) ? sh[t - off] : 0u;
    __syncthreads();
    sh[t] = v + a;
    __syncthreads();
  }
  uint incl = sh[t], base = incl - partial;
  if ((uint)r >= base && (uint)r < incl) {   // exactly one thread
    uint cum = base;
    for (int i = 0; i < 64; ++i) {
      uint c = hist[t * 64 + i];
      if ((uint)r < cum + c) {
        ctrl->binsel = t * 64 + i;
        ctrl->r_in = (int)((uint)r - cum);
        break;
      }
      cum += c;
    }
  }
}

// Collect candidates whose top-16 bits match the selected bin (~250 expected).
__global__ void k_cand(const uint* __restrict__ key32, int N, Ctrl* ctrl,
                       ull* __restrict__ cand) {
  int e = blockIdx.x * blockDim.x + threadIdx.x;
  if (e >= N) return;
  uint k = key32[e];
  if ((int)(k >> 16) == ctrl->binsel) {
    int p = atomicAdd(&ctrl->ncand, 1);
    if (p < CAND_CAP) cand[p] = ((ull)k << 32) | (uint)e;
  }
}

// One block: rank candidates by packed (key,idx); threshold = rank r_in element.
__global__ void k_pick1(const ull* __restrict__ cand, Ctrl* ctrl) {
  int nc = ctrl->ncand;
  if (nc > CAND_CAP) nc = CAND_CAP;
  int r = ctrl->r_in;
  for (int o = threadIdx.x; o < nc; o += blockDim.x) {
    ull my = cand[o];
    int cnt = 0;
    for (int i = 0; i < nc; ++i) cnt += (cand[i] < my) ? 1 : 0;
    if (cnt == r) ctrl->Tpack = my;   // exactly one (packs are unique)
  }
}

__device__ __forceinline__ int keptf(uint k, int e, ull T) {
  return ((((ull)k << 32) | (uint)e) > T) ? 1 : 0;
}

// Once-only: per-thread packed (excl-pos<<4)|flags, per-chunk sums, mask output.
__global__ void k_scanA(const uint* __restrict__ key32, const Ctrl* __restrict__ ctrl,
                        int* __restrict__ pw, int* __restrict__ bs,
                        float* __restrict__ mask_out) {
  __shared__ int sh[256];
  int t = threadIdx.x, blk = blockIdx.x;
  ull T = ctrl->Tpack;
  uint4 k4 = ((const uint4*)key32)[blk * 256 + t];
  int e0 = blk * 1024 + t * 4;
  int f0 = keptf(k4.x, e0, T), f1 = keptf(k4.y, e0 + 1, T);
  int f2 = keptf(k4.z, e0 + 2, T), f3 = keptf(k4.w, e0 + 3, T);
  int c = f0 + f1 + f2 + f3;
  sh[t] = c;
  __syncthreads();
  for (int off = 1; off < 256; off <<= 1) {
    int v = sh[t];
    int a = (t >= off) ? sh[t - off] : 0;
    __syncthreads();
    sh[t] = v + a;
    __syncthreads();
  }
  int excl = sh[t] - c;
  pw[blk * 256 + t] = (excl << 4) | f0 | (f1 << 1) | (f2 << 2) | (f3 << 3);
  ((float4*)mask_out)[blk * 256 + t] =
      make_float4((float)f0, (float)f1, (float)f2, (float)f3);
  if (t == 255) bs[blk] = sh[255];
}

// Exclusive scan of <=256 chunk counts.
__global__ void k_scanB(int* bs, int nb) {
  __shared__ int sh[256];
  int t = threadIdx.x;
  int v = (t < nb) ? bs[t] : 0;
  sh[t] = v;
  __syncthreads();
  for (int off = 1; off < 256; off <<= 1) {
    int x = sh[t];
    int a = (t >= off) ? sh[t - off] : 0;
    __syncthreads();
    sh[t] = x + a;
    __syncthreads();
  }
  if (t < nb) bs[t] = sh[t] - v;
}

// Compaction: no scan, no recompute. LDS-pack all 3 rows, stream out with
// aligned float4 stores (scalar head/tail). grid = (chunk, batch).
__global__ void __launch_bounds__(256)
k_compact(const int* __restrict__ pw, const int* __restrict__ bs,
          const int* __restrict__ ei, const float* __restrict__ attr,
          ll E, int N, int Kkeep, ll BK, float* __restrict__ out) {
  __shared__ float lds[3 * 1024];
  __shared__ int s_cnt;
  int t = threadIdx.x, blk = blockIdx.x, b = blockIdx.y;
  int q = blk * 256 + t;
  int w = pw[q];
  int f = w & 15;
  int o = w >> 4;
  ll cb = (ll)b * N;
  int4 d0 = ((const int4*)(ei + cb))[q];
  int4 d1 = ((const int4*)(ei + E + cb))[q];
  float4 d2 = ((const float4*)(attr + cb))[q];
  float* l0 = lds;
  float* l1 = lds + 1024;
  float* l2 = lds + 2048;
  if (f & 1) { l0[o] = (float)d0.x; l1[o] = (float)d1.x; l2[o] = d2.x; o++; }
  if (f & 2) { l0[o] = (float)d0.y; l1[o] = (float)d1.y; l2[o] = d2.y; o++; }
  if (f & 4) { l0[o] = (float)d0.z; l1[o] = (float)d1.z; l2[o] = d2.z; o++; }
  if (f & 8) { l0[o] = (float)d0.w; l1[o] = (float)d1.w; l2[o] = d2.w; }
  if (t == 255) s_cnt = (w >> 4) + __popc(f);
  __syncthreads();
  int cnt = s_cnt;
  ll ob = (ll)b * Kkeep + bs[blk];
  int al = (int)(ob & 3);
  int head = (4 - al) & 3;
  if (head > cnt) head = cnt;
  int rem = cnt - head;
  int nv = rem >> 2, tail = rem & 3;
  for (int r = 0; r < 3; ++r) {
    float* dst = out + (ll)r * BK + ob;
    const float* src = lds + r * 1024;
    if (t < head) dst[t] = src[t];
    for (int i = t; i < nv; i += 256) {
      int s = head + 4 * i;
      float4 v = make_float4(src[s], src[s + 1], src[s + 2], src[s + 3]);
      *(float4*)(dst + s) = v;   // dst+s is 16B-aligned by construction
    }
    if (t < tail) { int s = head + 4 * nv + t; dst[s] = src[s]; }
  }
}

extern "C" void kernel_launch(void* const* d_in, const int* in_sizes, int n_in,
                              void* d_out, int out_size, void* d_ws, size_t ws_size,
                              hipStream_t stream) {
  const int* ei = (const int*)d_in[0];
  const float* attr = (const float*)d_in[1];
  const float* wm = (const float*)d_in[3];

  int B = in_sizes[2] - 1;                          // 64
  ll E = (ll)in_sizes[0] / 2;                       // 16777216
  int e_per = (int)(E / B);                         // 262144
  int D = (int)llround(sqrt((double)in_sizes[3]));  // 4096
  int num_rm = (int)((double)e_per * 0.3);          // 78643
  int Kkeep = e_per - num_rm;                       // 183501
  ll BK = (ll)B * Kkeep;
  int nb = (e_per + 1023) / 1024;                   // 256

  char* w = (char*)d_ws;
  size_t off = 0;
  uint* key32 = (uint*)(w + off);  off += (size_t)e_per * 4;
  uint* hist = (uint*)(w + off);   off += 65536 * 4;
  Ctrl* ctrl = (Ctrl*)(w + off);   off += 64;
  ull* cand = (ull*)(w + off);     off += (size_t)CAND_CAP * 8;
  int* bs = (int*)(w + off);       off += 1024;
  int* pw = (int*)(w + off);       off += (size_t)(e_per / 4) * 4;
  (void)ws_size; (void)n_in; (void)out_size;

  float* out = (float*)d_out;
  float* mask_out = out + 3 * BK;

  hipMemsetAsync(hist, 0, 65536 * 4 + sizeof(Ctrl), stream);
  k_keys<<<dim3(nb), dim3(1024), 0, stream>>>(ei, wm, e_per, E, D, key32, hist);
  k_pick0<<<dim3(1), dim3(1024), 0, stream>>>(hist, num_rm - 1, ctrl);
  k_cand<<<dim3(nb), dim3(1024), 0, stream>>>(key32, e_per, ctrl, cand);
  k_pick1<<<dim3(1), dim3(1024), 0, stream>>>(cand, ctrl);
  k_scanA<<<dim3(nb), dim3(256), 0, stream>>>(key32, ctrl, pw, bs, mask_out);
  k_scanB<<<dim3(1), dim3(256), 0, stream>>>(bs, nb);
  k_compact<<<dim3(nb, B), dim3(256), 0, stream>>>(pw, bs, ei, attr,
                                                   E, e_per, Kkeep, BK, out);
}

// Round 6
// 119.645 us; speedup vs baseline: 2.8676x; 1.5245x over previous
//
#include <hip/hip_runtime.h>
#include <stdint.h>
#include <math.h>

#define CAND_CAP 8192
typedef unsigned long long ull;
typedef long long ll;
typedef unsigned int uint;

struct Ctrl {
  int sel0;     // selected top-8 bin
  int r0;       // remaining rank within top-8 bin
  int binsel;   // selected top-16 bin
  int r_in;     // remaining rank within top-16 bin
  int ncand;    // candidate count (atomic)
  int pad;
  ull Tpack;    // packed (key32<<32)|idx of threshold element
};

__device__ __forceinline__ uint fkey(float f) {
  uint u = __float_as_uint(f);
  return (u & 0x80000000u) ? ~u : (u | 0x80000000u);
}

// 4 edges/thread: int4 edge loads, 8 independent wm gathers (MLP), uint4 key write.
// Level-0 (top-8-bit) histogram LDS-aggregated, flushed as <=256 atomics/block.
__global__ void __launch_bounds__(256) k_keys(
    const int* __restrict__ ei, const float* __restrict__ wm,
    ll E, int D, uint* __restrict__ key32, uint* __restrict__ hist0) {
  __shared__ uint sh[256];
  int t = threadIdx.x;
  sh[t] = 0u;
  __syncthreads();
  int v = blockIdx.x * 256 + t;   // v indexes groups of 4 edges
  int4 s4 = ((const int4*)ei)[v];
  int4 d4 = ((const int4*)(ei + E))[v];
  float a0 = wm[(ll)s4.x * D + d4.x], b0 = wm[(ll)d4.x * D + s4.x];
  float a1 = wm[(ll)s4.y * D + d4.y], b1 = wm[(ll)d4.y * D + s4.y];
  float a2 = wm[(ll)s4.z * D + d4.z], b2 = wm[(ll)d4.z * D + s4.z];
  float a3 = wm[(ll)s4.w * D + d4.w], b3 = wm[(ll)d4.w * D + s4.w];
  uint4 k;
  k.x = fkey((float)((double)a0 + (double)b0));
  k.y = fkey((float)((double)a1 + (double)b1));
  k.z = fkey((float)((double)a2 + (double)b2));
  k.w = fkey((float)((double)a3 + (double)b3));
  ((uint4*)key32)[v] = k;
  atomicAdd(&sh[k.x >> 24], 1u);
  atomicAdd(&sh[k.y >> 24], 1u);
  atomicAdd(&sh[k.z >> 24], 1u);
  atomicAdd(&sh[k.w >> 24], 1u);
  __syncthreads();
  if (sh[t]) atomicAdd(&hist0[t], sh[t]);
}

// One block, 256 threads: scan 256 bins, pick bin containing rank r.
__global__ void k_pick0(const uint* __restrict__ hist0, int r, Ctrl* ctrl) {
  __shared__ uint sh[256];
  int t = threadIdx.x;
  uint c = hist0[t];
  sh[t] = c;
  __syncthreads();
  for (int off = 1; off < 256; off <<= 1) {
    uint v = sh[t];
    uint a = (t >= off) ? sh[t - off] : 0u;
    __syncthreads();
    sh[t] = v + a;
    __syncthreads();
  }
  uint incl = sh[t], excl = incl - c;
  if ((uint)r >= excl && (uint)r < incl) {  // exactly one thread
    ctrl->sel0 = t;
    ctrl->r0 = (int)((uint)r - excl);
  }
}

// Level-1: LDS hist of bits 16..23 among elements whose top-8 == sel0.
__global__ void __launch_bounds__(256) k_hist1(
    const uint* __restrict__ key32, const Ctrl* __restrict__ ctrl,
    uint* __restrict__ hist1) {
  __shared__ uint sh[256];
  int t = threadIdx.x;
  sh[t] = 0u;
  __syncthreads();
  uint sel0 = (uint)ctrl->sel0;
  uint4 k = ((const uint4*)key32)[blockIdx.x * 256 + t];
  if ((k.x >> 24) == sel0) atomicAdd(&sh[(k.x >> 16) & 0xFFu], 1u);
  if ((k.y >> 24) == sel0) atomicAdd(&sh[(k.y >> 16) & 0xFFu], 1u);
  if ((k.z >> 24) == sel0) atomicAdd(&sh[(k.z >> 16) & 0xFFu], 1u);
  if ((k.w >> 24) == sel0) atomicAdd(&sh[(k.w >> 16) & 0xFFu], 1u);
  __syncthreads();
  if (sh[t]) atomicAdd(&hist1[t], sh[t]);
}

__global__ void k_pick1(const uint* __restrict__ hist1, Ctrl* ctrl) {
  __shared__ uint sh[256];
  int t = threadIdx.x;
  uint c = hist1[t];
  sh[t] = c;
  __syncthreads();
  for (int off = 1; off < 256; off <<= 1) {
    uint v = sh[t];
    uint a = (t >= off) ? sh[t - off] : 0u;
    __syncthreads();
    sh[t] = v + a;
    __syncthreads();
  }
  uint incl = sh[t], excl = incl - c;
  uint r = (uint)ctrl->r0;
  if (r >= excl && r < incl) {  // exactly one thread
    ctrl->binsel = (ctrl->sel0 << 8) | t;
    ctrl->r_in = (int)(r - excl);
  }
}

// Collect candidates whose top-16 bits match binsel (~500 expected).
__global__ void k_cand(const uint* __restrict__ key32, int N, Ctrl* ctrl,
                       ull* __restrict__ cand) {
  int e = blockIdx.x * blockDim.x + threadIdx.x;
  if (e >= N) return;
  uint k = key32[e];
  if ((int)(k >> 16) == ctrl->binsel) {
    int p = atomicAdd(&ctrl->ncand, 1);
    if (p < CAND_CAP) cand[p] = ((ull)k << 32) | (uint)e;
  }
}

// Rank candidates by packed (key,idx); threshold = rank r_in element.
__global__ void k_pickT(const ull* __restrict__ cand, Ctrl* ctrl) {
  int nc = ctrl->ncand;
  if (nc > CAND_CAP) nc = CAND_CAP;
  int r = ctrl->r_in;
  for (int o = threadIdx.x; o < nc; o += blockDim.x) {
    ull my = cand[o];
    int cnt = 0;
    for (int i = 0; i < nc; ++i) cnt += (cand[i] < my) ? 1 : 0;
    if (cnt == r) ctrl->Tpack = my;   // exactly one (packs are unique)
  }
}

__device__ __forceinline__ int keptf(uint k, int e, ull T) {
  return ((((ull)k << 32) | (uint)e) > T) ? 1 : 0;
}

// Once-only: per-thread packed (excl-pos<<4)|flags, per-chunk sums, mask output.
__global__ void __launch_bounds__(256) k_scanA(
    const uint* __restrict__ key32, const Ctrl* __restrict__ ctrl,
    int* __restrict__ pw, int* __restrict__ bs, float* __restrict__ mask_out) {
  __shared__ int sh[256];
  int t = threadIdx.x, blk = blockIdx.x;
  ull T = ctrl->Tpack;
  uint4 k4 = ((const uint4*)key32)[blk * 256 + t];
  int e0 = blk * 1024 + t * 4;
  int f0 = keptf(k4.x, e0, T), f1 = keptf(k4.y, e0 + 1, T);
  int f2 = keptf(k4.z, e0 + 2, T), f3 = keptf(k4.w, e0 + 3, T);
  int c = f0 + f1 + f2 + f3;
  sh[t] = c;
  __syncthreads();
  for (int off = 1; off < 256; off <<= 1) {
    int v = sh[t];
    int a = (t >= off) ? sh[t - off] : 0;
    __syncthreads();
    sh[t] = v + a;
    __syncthreads();
  }
  int excl = sh[t] - c;
  pw[blk * 256 + t] = (excl << 4) | f0 | (f1 << 1) | (f2 << 2) | (f3 << 3);
  ((float4*)mask_out)[blk * 256 + t] =
      make_float4((float)f0, (float)f1, (float)f2, (float)f3);
  if (t == 255) bs[blk] = sh[255];
}

__global__ void k_scanB(int* bs, int nb) {
  __shared__ int sh[256];
  int t = threadIdx.x;
  int v = (t < nb) ? bs[t] : 0;
  sh[t] = v;
  __syncthreads();
  for (int off = 1; off < 256; off <<= 1) {
    int x = sh[t];
    int a = (t >= off) ? sh[t - off] : 0;
    __syncthreads();
    sh[t] = x + a;
    __syncthreads();
  }
  if (t < nb) bs[t] = sh[t] - v;
}

// Compaction: LDS staging aligned to the OUTPUT 16B phase; drain with aligned
// float4 LDS reads + aligned float4 global stores (guards only on 2 boundary
// slots per row). grid = (chunk, batch).
__global__ void __launch_bounds__(256) k_compact(
    const int* __restrict__ pw, const int* __restrict__ bs,
    const int* __restrict__ ei, const float* __restrict__ attr,
    ll E, int N, int Kkeep, ll BK, float* __restrict__ out) {
  __shared__ float lds[3][1028];
  __shared__ int s_cnt;
  int t = threadIdx.x, blk = blockIdx.x, b = blockIdx.y;
  int q = blk * 256 + t;
  int w = pw[q];
  int f = w & 15;
  int o0 = w >> 4;
  ll cb = (ll)b * N;
  int4 d0 = ((const int4*)(ei + cb))[q];
  int4 d1 = ((const int4*)(ei + E + cb))[q];
  float4 d2 = ((const float4*)(attr + cb))[q];
  ll ob = (ll)b * (ll)Kkeep + (ll)bs[blk];
  int al = (int)(ob & 3);
  int p = o0 + al;   // stage shifted so LDS index == global index mod 4
  if (f & 1) { lds[0][p] = (float)d0.x; lds[1][p] = (float)d1.x; lds[2][p] = d2.x; p++; }
  if (f & 2) { lds[0][p] = (float)d0.y; lds[1][p] = (float)d1.y; lds[2][p] = d2.y; p++; }
  if (f & 4) { lds[0][p] = (float)d0.z; lds[1][p] = (float)d1.z; lds[2][p] = d2.z; p++; }
  if (f & 8) { lds[0][p] = (float)d0.w; lds[1][p] = (float)d1.w; lds[2][p] = d2.w; }
  if (t == 255) s_cnt = o0 + __popc(f);
  __syncthreads();
  int cnt = s_cnt;
  int lo = al, hi = al + cnt;          // valid LDS index range
  int nslot = (hi + 3) >> 2;
  ll gbase = ob - al;                  // 16B-aligned global base
  for (int r = 0; r < 3; ++r) {
    const float* src = lds[r];
    float* dst = out + (ll)r * BK + gbase;
    for (int i = t; i < nslot; i += 256) {
      int j0 = 4 * i;
      float4 v = *(const float4*)(src + j0);
      if (j0 >= lo && j0 + 3 < hi) {
        *(float4*)(dst + j0) = v;
      } else {
        if (j0 >= lo && j0 < hi)         dst[j0]     = v.x;
        if (j0 + 1 >= lo && j0 + 1 < hi) dst[j0 + 1] = v.y;
        if (j0 + 2 >= lo && j0 + 2 < hi) dst[j0 + 2] = v.z;
        if (j0 + 3 >= lo && j0 + 3 < hi) dst[j0 + 3] = v.w;
      }
    }
  }
}

extern "C" void kernel_launch(void* const* d_in, const int* in_sizes, int n_in,
                              void* d_out, int out_size, void* d_ws, size_t ws_size,
                              hipStream_t stream) {
  const int* ei = (const int*)d_in[0];
  const float* attr = (const float*)d_in[1];
  const float* wm = (const float*)d_in[3];

  int B = in_sizes[2] - 1;                          // 64
  ll E = (ll)in_sizes[0] / 2;                       // 16777216
  int e_per = (int)(E / B);                         // 262144
  int D = (int)llround(sqrt((double)in_sizes[3]));  // 4096
  int num_rm = (int)((double)e_per * 0.3);          // 78643
  int Kkeep = e_per - num_rm;                       // 183501
  ll BK = (ll)B * Kkeep;
  int nb = (e_per + 1023) / 1024;                   // 256

  char* w = (char*)d_ws;
  size_t off = 0;
  uint* key32 = (uint*)(w + off);  off += (size_t)e_per * 4;
  uint* hist0 = (uint*)(w + off);  off += 256 * 4;
  uint* hist1 = (uint*)(w + off);  off += 256 * 4;
  Ctrl* ctrl = (Ctrl*)(w + off);   off += 64;
  ull* cand = (ull*)(w + off);     off += (size_t)CAND_CAP * 8;
  int* bs = (int*)(w + off);       off += 1024;
  int* pw = (int*)(w + off);       off += (size_t)(e_per / 4) * 4;
  (void)ws_size; (void)n_in; (void)out_size;

  float* out = (float*)d_out;
  float* mask_out = out + 3 * BK;

  hipMemsetAsync(hist0, 0, 256 * 4 + 256 * 4 + 64, stream);
  k_keys<<<dim3(e_per / 1024), dim3(256), 0, stream>>>(ei, wm, E, D, key32, hist0);
  k_pick0<<<dim3(1), dim3(256), 0, stream>>>(hist0, num_rm - 1, ctrl);
  k_hist1<<<dim3(e_per / 1024), dim3(256), 0, stream>>>(key32, ctrl, hist1);
  k_pick1<<<dim3(1), dim3(256), 0, stream>>>(hist1, ctrl);
  k_cand<<<dim3(nb), dim3(1024), 0, stream>>>(key32, e_per, ctrl, cand);
  k_pickT<<<dim3(1), dim3(1024), 0, stream>>>(cand, ctrl);
  k_scanA<<<dim3(nb), dim3(256), 0, stream>>>(key32, ctrl, pw, bs, mask_out);
  k_scanB<<<dim3(1), dim3(256), 0, stream>>>(bs, nb);
  k_compact<<<dim3(nb, B), dim3(256), 0, stream>>>(pw, bs, ei, attr,
                                                   E, e_per, Kkeep, BK, out);
}

// Round 7
// 117.666 us; speedup vs baseline: 2.9158x; 1.0168x over previous
//
#include <hip/hip_runtime.h>
#include <stdint.h>
#include <math.h>

#define CAND_CAP 8192
typedef unsigned long long ull;
typedef long long ll;
typedef unsigned int uint;
typedef float __attribute__((ext_vector_type(4))) f4;
typedef int __attribute__((ext_vector_type(4))) i4;

struct Ctrl {
  int sel0;     // selected top-8 bin
  int r0;       // remaining rank within top-8 bin
  int binsel;   // selected top-16 bin
  int r_in;     // remaining rank within top-16 bin
  int ncand;    // candidate count (atomic)
  int pad;
  ull Tpack;    // packed (key32<<32)|idx of threshold element
};

__device__ __forceinline__ uint fkey(float f) {
  uint u = __float_as_uint(f);
  return (u & 0x80000000u) ? ~u : (u | 0x80000000u);
}

// 4 edges/thread: int4 edge loads, 8 independent wm gathers (MLP), uint4 key write.
// Level-0 (top-8-bit) histogram LDS-aggregated, flushed as <=256 atomics/block.
__global__ void __launch_bounds__(256) k_keys(
    const int* __restrict__ ei, const float* __restrict__ wm,
    ll E, int D, uint* __restrict__ key32, uint* __restrict__ hist0) {
  __shared__ uint sh[256];
  int t = threadIdx.x;
  sh[t] = 0u;
  __syncthreads();
  int v = blockIdx.x * 256 + t;   // v indexes groups of 4 edges
  int4 s4 = ((const int4*)ei)[v];
  int4 d4 = ((const int4*)(ei + E))[v];
  float a0 = wm[(ll)s4.x * D + d4.x], b0 = wm[(ll)d4.x * D + s4.x];
  float a1 = wm[(ll)s4.y * D + d4.y], b1 = wm[(ll)d4.y * D + s4.y];
  float a2 = wm[(ll)s4.z * D + d4.z], b2 = wm[(ll)d4.z * D + s4.z];
  float a3 = wm[(ll)s4.w * D + d4.w], b3 = wm[(ll)d4.w * D + s4.w];
  uint4 k;
  k.x = fkey((float)((double)a0 + (double)b0));
  k.y = fkey((float)((double)a1 + (double)b1));
  k.z = fkey((float)((double)a2 + (double)b2));
  k.w = fkey((float)((double)a3 + (double)b3));
  ((uint4*)key32)[v] = k;
  atomicAdd(&sh[k.x >> 24], 1u);
  atomicAdd(&sh[k.y >> 24], 1u);
  atomicAdd(&sh[k.z >> 24], 1u);
  atomicAdd(&sh[k.w >> 24], 1u);
  __syncthreads();
  if (sh[t]) atomicAdd(&hist0[t], sh[t]);
}

// One block, 256 threads: scan 256 bins, pick bin containing rank r.
__global__ void k_pick0(const uint* __restrict__ hist0, int r, Ctrl* ctrl) {
  __shared__ uint sh[256];
  int t = threadIdx.x;
  uint c = hist0[t];
  sh[t] = c;
  __syncthreads();
  for (int off = 1; off < 256; off <<= 1) {
    uint v = sh[t];
    uint a = (t >= off) ? sh[t - off] : 0u;
    __syncthreads();
    sh[t] = v + a;
    __syncthreads();
  }
  uint incl = sh[t], excl = incl - c;
  if ((uint)r >= excl && (uint)r < incl) {  // exactly one thread
    ctrl->sel0 = t;
    ctrl->r0 = (int)((uint)r - excl);
  }
}

// Level-1: LDS hist of bits 16..23 among elements whose top-8 == sel0.
__global__ void __launch_bounds__(256) k_hist1(
    const uint* __restrict__ key32, const Ctrl* __restrict__ ctrl,
    uint* __restrict__ hist1) {
  __shared__ uint sh[256];
  int t = threadIdx.x;
  sh[t] = 0u;
  __syncthreads();
  uint sel0 = (uint)ctrl->sel0;
  uint4 k = ((const uint4*)key32)[blockIdx.x * 256 + t];
  if ((k.x >> 24) == sel0) atomicAdd(&sh[(k.x >> 16) & 0xFFu], 1u);
  if ((k.y >> 24) == sel0) atomicAdd(&sh[(k.y >> 16) & 0xFFu], 1u);
  if ((k.z >> 24) == sel0) atomicAdd(&sh[(k.z >> 16) & 0xFFu], 1u);
  if ((k.w >> 24) == sel0) atomicAdd(&sh[(k.w >> 16) & 0xFFu], 1u);
  __syncthreads();
  if (sh[t]) atomicAdd(&hist1[t], sh[t]);
}

__global__ void k_pick1(const uint* __restrict__ hist1, Ctrl* ctrl) {
  __shared__ uint sh[256];
  int t = threadIdx.x;
  uint c = hist1[t];
  sh[t] = c;
  __syncthreads();
  for (int off = 1; off < 256; off <<= 1) {
    uint v = sh[t];
    uint a = (t >= off) ? sh[t - off] : 0u;
    __syncthreads();
    sh[t] = v + a;
    __syncthreads();
  }
  uint incl = sh[t], excl = incl - c;
  uint r = (uint)ctrl->r0;
  if (r >= excl && r < incl) {  // exactly one thread
    ctrl->binsel = (ctrl->sel0 << 8) | t;
    ctrl->r_in = (int)(r - excl);
  }
}

// Collect candidates whose top-16 bits match binsel (~500 expected).
__global__ void k_cand(const uint* __restrict__ key32, int N, Ctrl* ctrl,
                       ull* __restrict__ cand) {
  int e = blockIdx.x * blockDim.x + threadIdx.x;
  if (e >= N) return;
  uint k = key32[e];
  if ((int)(k >> 16) == ctrl->binsel) {
    int p = atomicAdd(&ctrl->ncand, 1);
    if (p < CAND_CAP) cand[p] = ((ull)k << 32) | (uint)e;
  }
}

// Rank candidates by packed (key,idx); threshold = rank r_in element.
__global__ void k_pickT(const ull* __restrict__ cand, Ctrl* ctrl) {
  int nc = ctrl->ncand;
  if (nc > CAND_CAP) nc = CAND_CAP;
  int r = ctrl->r_in;
  for (int o = threadIdx.x; o < nc; o += blockDim.x) {
    ull my = cand[o];
    int cnt = 0;
    for (int i = 0; i < nc; ++i) cnt += (cand[i] < my) ? 1 : 0;
    if (cnt == r) ctrl->Tpack = my;   // exactly one (packs are unique)
  }
}

__device__ __forceinline__ int keptf(uint k, int e, ull T) {
  return ((((ull)k << 32) | (uint)e) > T) ? 1 : 0;
}

// Once-only: per-thread packed (excl-pos<<4)|flags, per-chunk sums, mask output.
__global__ void __launch_bounds__(256) k_scanA(
    const uint* __restrict__ key32, const Ctrl* __restrict__ ctrl,
    int* __restrict__ pw, int* __restrict__ bs, float* __restrict__ mask_out) {
  __shared__ int sh[256];
  int t = threadIdx.x, blk = blockIdx.x;
  ull T = ctrl->Tpack;
  uint4 k4 = ((const uint4*)key32)[blk * 256 + t];
  int e0 = blk * 1024 + t * 4;
  int f0 = keptf(k4.x, e0, T), f1 = keptf(k4.y, e0 + 1, T);
  int f2 = keptf(k4.z, e0 + 2, T), f3 = keptf(k4.w, e0 + 3, T);
  int c = f0 + f1 + f2 + f3;
  sh[t] = c;
  __syncthreads();
  for (int off = 1; off < 256; off <<= 1) {
    int v = sh[t];
    int a = (t >= off) ? sh[t - off] : 0;
    __syncthreads();
    sh[t] = v + a;
    __syncthreads();
  }
  int excl = sh[t] - c;
  pw[blk * 256 + t] = (excl << 4) | f0 | (f1 << 1) | (f2 << 2) | (f3 << 3);
  ((float4*)mask_out)[blk * 256 + t] =
      make_float4((float)f0, (float)f1, (float)f2, (float)f3);
  if (t == 255) bs[blk] = sh[255];
}

__global__ void k_scanB(int* bs, int nb) {
  __shared__ int sh[256];
  int t = threadIdx.x;
  int v = (t < nb) ? bs[t] : 0;
  sh[t] = v;
  __syncthreads();
  for (int off = 1; off < 256; off <<= 1) {
    int x = sh[t];
    int a = (t >= off) ? sh[t - off] : 0;
    __syncthreads();
    sh[t] = x + a;
    __syncthreads();
  }
  if (t < nb) bs[t] = sh[t] - v;
}

// Wave-autonomous compaction: each wave (64 threads) independently compacts a
// 256-element sub-chunk into its private LDS region and drains with aligned
// float4 nontemporal stores. NO __syncthreads. grid = (chunk, batch).
__global__ void __launch_bounds__(256) k_compact(
    const int* __restrict__ pw, const int* __restrict__ bs,
    const int* __restrict__ ei, const float* __restrict__ attr,
    ll E, int N, int Kkeep, ll BK, float* __restrict__ out) {
  __shared__ float lds[4][3][264];   // [wave][row][slot], 16B-aligned rows
  int t = threadIdx.x;
  int w = t >> 6;       // wave id
  int l = t & 63;       // lane
  int blk = blockIdx.x, b = blockIdx.y;
  int q = blk * 256 + t;            // pw slot; elems 4q..4q+3
  int wv = pw[q];
  int flags = wv & 15;
  int excl = wv >> 4;               // kept-count before elem 4q within 1024-chunk
  int subbase = __shfl(excl, 0);    // wave's sub-chunk base within chunk
  int wlast = __shfl(wv, 63);
  int cnt = (wlast >> 4) + __popc(wlast & 15) - subbase;   // kept in sub-chunk
  ll cb = (ll)b * N;
  i4 d0 = __builtin_nontemporal_load((const i4*)(ei + cb) + q);
  i4 d1 = __builtin_nontemporal_load((const i4*)(ei + E + cb) + q);
  f4 d2 = __builtin_nontemporal_load((const f4*)(attr + cb) + q);
  ll ob = (ll)b * Kkeep + bs[blk] + subbase;   // global out pos of wave span
  int al = (int)(ob & 3);
  int p = (excl - subbase) + al;    // stage shifted to output 16B phase
  float* L0 = lds[w][0];
  float* L1 = lds[w][1];
  float* L2 = lds[w][2];
  if (flags & 1) { L0[p] = (float)d0.x; L1[p] = (float)d1.x; L2[p] = d2.x; p++; }
  if (flags & 2) { L0[p] = (float)d0.y; L1[p] = (float)d1.y; L2[p] = d2.y; p++; }
  if (flags & 4) { L0[p] = (float)d0.z; L1[p] = (float)d1.z; L2[p] = d2.z; p++; }
  if (flags & 8) { L0[p] = (float)d0.w; L1[p] = (float)d1.w; L2[p] = d2.w; }
  __threadfence_block();            // order LDS writes before wave's own reads
  int lo = al, hi = al + cnt;       // valid LDS index range (wave-uniform)
  int nslot = (hi + 3) >> 2;        // up to 65 -> loop may run twice for lane<1
  ll gbase = ob - al;               // 16B-aligned global base
  #pragma unroll
  for (int r = 0; r < 3; ++r) {
    const float* src = lds[w][r];
    float* dst = out + (ll)r * BK + gbase;
    for (int i = l; i < nslot; i += 64) {
      int j0 = 4 * i;
      f4 v = *(const f4*)(src + j0);
      if (j0 >= lo && j0 + 3 < hi) {
        __builtin_nontemporal_store(v, (f4*)(dst + j0));
      } else {
        if (j0 >= lo && j0 < hi)         __builtin_nontemporal_store(v.x, dst + j0);
        if (j0 + 1 >= lo && j0 + 1 < hi) __builtin_nontemporal_store(v.y, dst + j0 + 1);
        if (j0 + 2 >= lo && j0 + 2 < hi) __builtin_nontemporal_store(v.z, dst + j0 + 2);
        if (j0 + 3 >= lo && j0 + 3 < hi) __builtin_nontemporal_store(v.w, dst + j0 + 3);
      }
    }
  }
}

extern "C" void kernel_launch(void* const* d_in, const int* in_sizes, int n_in,
                              void* d_out, int out_size, void* d_ws, size_t ws_size,
                              hipStream_t stream) {
  const int* ei = (const int*)d_in[0];
  const float* attr = (const float*)d_in[1];
  const float* wm = (const float*)d_in[3];

  int B = in_sizes[2] - 1;                          // 64
  ll E = (ll)in_sizes[0] / 2;                       // 16777216
  int e_per = (int)(E / B);                         // 262144
  int D = (int)llround(sqrt((double)in_sizes[3]));  // 4096
  int num_rm = (int)((double)e_per * 0.3);          // 78643
  int Kkeep = e_per - num_rm;                       // 183501
  ll BK = (ll)B * Kkeep;
  int nb = (e_per + 1023) / 1024;                   // 256

  char* w = (char*)d_ws;
  size_t off = 0;
  uint* key32 = (uint*)(w + off);  off += (size_t)e_per * 4;
  uint* hist0 = (uint*)(w + off);  off += 256 * 4;
  uint* hist1 = (uint*)(w + off);  off += 256 * 4;
  Ctrl* ctrl = (Ctrl*)(w + off);   off += 64;
  ull* cand = (ull*)(w + off);     off += (size_t)CAND_CAP * 8;
  int* bs = (int*)(w + off);       off += 1024;
  int* pw = (int*)(w + off);       off += (size_t)(e_per / 4) * 4;
  (void)ws_size; (void)n_in; (void)out_size;

  float* out = (float*)d_out;
  float* mask_out = out + 3 * BK;

  hipMemsetAsync(hist0, 0, 256 * 4 + 256 * 4 + 64, stream);
  k_keys<<<dim3(e_per / 1024), dim3(256), 0, stream>>>(ei, wm, E, D, key32, hist0);
  k_pick0<<<dim3(1), dim3(256), 0, stream>>>(hist0, num_rm - 1, ctrl);
  k_hist1<<<dim3(e_per / 1024), dim3(256), 0, stream>>>(key32, ctrl, hist1);
  k_pick1<<<dim3(1), dim3(256), 0, stream>>>(hist1, ctrl);
  k_cand<<<dim3(nb), dim3(1024), 0, stream>>>(key32, e_per, ctrl, cand);
  k_pickT<<<dim3(1), dim3(1024), 0, stream>>>(cand, ctrl);
  k_scanA<<<dim3(nb), dim3(256), 0, stream>>>(key32, ctrl, pw, bs, mask_out);
  k_scanB<<<dim3(1), dim3(256), 0, stream>>>(bs, nb);
  k_compact<<<dim3(nb, B), dim3(256), 0, stream>>>(pw, bs, ei, attr,
                                                   E, e_per, Kkeep, BK, out);
}

// Round 8
// 112.250 us; speedup vs baseline: 3.0565x; 1.0483x over previous
//
#include <hip/hip_runtime.h>
#include <stdint.h>
#include <math.h>

#define CAND_CAP 8192
typedef unsigned long long ull;
typedef long long ll;
typedef unsigned int uint;
typedef float __attribute__((ext_vector_type(4))) f4;
typedef int __attribute__((ext_vector_type(4))) i4;

struct Ctrl {
  int sel0;     // selected top-8 bin
  int r0;       // remaining rank within top-8 bin
  int binsel;   // selected top-16 bin
  int r_in;     // remaining rank within top-16 bin
  int ncand;    // candidate count (atomic)
  int pad;
  ull Tpack;    // packed (key32<<32)|idx of threshold element
};

__device__ __forceinline__ uint fkey(float f) {
  uint u = __float_as_uint(f);
  return (u & 0x80000000u) ? ~u : (u | 0x80000000u);
}

// 4 edges/thread: int4 edge loads, 8 independent wm gathers (MLP), uint4 key write.
// Level-0 (top-8-bit) histogram LDS-aggregated, flushed as <=256 atomics/block.
__global__ void __launch_bounds__(256) k_keys(
    const int* __restrict__ ei, const float* __restrict__ wm,
    ll E, int D, uint* __restrict__ key32, uint* __restrict__ hist0) {
  __shared__ uint sh[256];
  int t = threadIdx.x;
  sh[t] = 0u;
  __syncthreads();
  int v = blockIdx.x * 256 + t;   // v indexes groups of 4 edges
  int4 s4 = ((const int4*)ei)[v];
  int4 d4 = ((const int4*)(ei + E))[v];
  float a0 = wm[(ll)s4.x * D + d4.x], b0 = wm[(ll)d4.x * D + s4.x];
  float a1 = wm[(ll)s4.y * D + d4.y], b1 = wm[(ll)d4.y * D + s4.y];
  float a2 = wm[(ll)s4.z * D + d4.z], b2 = wm[(ll)d4.z * D + s4.z];
  float a3 = wm[(ll)s4.w * D + d4.w], b3 = wm[(ll)d4.w * D + s4.w];
  uint4 k;
  k.x = fkey((float)((double)a0 + (double)b0));
  k.y = fkey((float)((double)a1 + (double)b1));
  k.z = fkey((float)((double)a2 + (double)b2));
  k.w = fkey((float)((double)a3 + (double)b3));
  ((uint4*)key32)[v] = k;
  atomicAdd(&sh[k.x >> 24], 1u);
  atomicAdd(&sh[k.y >> 24], 1u);
  atomicAdd(&sh[k.z >> 24], 1u);
  atomicAdd(&sh[k.w >> 24], 1u);
  __syncthreads();
  if (sh[t]) atomicAdd(&hist0[t], sh[t]);
}

// One block, 256 threads: scan 256 bins, pick bin containing rank r.
__global__ void k_pick0(const uint* __restrict__ hist0, int r, Ctrl* ctrl) {
  __shared__ uint sh[256];
  int t = threadIdx.x;
  uint c = hist0[t];
  sh[t] = c;
  __syncthreads();
  for (int off = 1; off < 256; off <<= 1) {
    uint v = sh[t];
    uint a = (t >= off) ? sh[t - off] : 0u;
    __syncthreads();
    sh[t] = v + a;
    __syncthreads();
  }
  uint incl = sh[t], excl = incl - c;
  if ((uint)r >= excl && (uint)r < incl) {  // exactly one thread
    ctrl->sel0 = t;
    ctrl->r0 = (int)((uint)r - excl);
  }
}

// Level-1: LDS hist of bits 16..23 among elements whose top-8 == sel0.
__global__ void __launch_bounds__(256) k_hist1(
    const uint* __restrict__ key32, const Ctrl* __restrict__ ctrl,
    uint* __restrict__ hist1) {
  __shared__ uint sh[256];
  int t = threadIdx.x;
  sh[t] = 0u;
  __syncthreads();
  uint sel0 = (uint)ctrl->sel0;
  uint4 k = ((const uint4*)key32)[blockIdx.x * 256 + t];
  if ((k.x >> 24) == sel0) atomicAdd(&sh[(k.x >> 16) & 0xFFu], 1u);
  if ((k.y >> 24) == sel0) atomicAdd(&sh[(k.y >> 16) & 0xFFu], 1u);
  if ((k.z >> 24) == sel0) atomicAdd(&sh[(k.z >> 16) & 0xFFu], 1u);
  if ((k.w >> 24) == sel0) atomicAdd(&sh[(k.w >> 16) & 0xFFu], 1u);
  __syncthreads();
  if (sh[t]) atomicAdd(&hist1[t], sh[t]);
}

__global__ void k_pick1(const uint* __restrict__ hist1, Ctrl* ctrl) {
  __shared__ uint sh[256];
  int t = threadIdx.x;
  uint c = hist1[t];
  sh[t] = c;
  __syncthreads();
  for (int off = 1; off < 256; off <<= 1) {
    uint v = sh[t];
    uint a = (t >= off) ? sh[t - off] : 0u;
    __syncthreads();
    sh[t] = v + a;
    __syncthreads();
  }
  uint incl = sh[t], excl = incl - c;
  uint r = (uint)ctrl->r0;
  if (r >= excl && r < incl) {  // exactly one thread
    ctrl->binsel = (ctrl->sel0 << 8) | t;
    ctrl->r_in = (int)(r - excl);
  }
}

// Collect candidates whose top-16 bits match binsel (~500 expected).
__global__ void k_cand(const uint* __restrict__ key32, int N, Ctrl* ctrl,
                       ull* __restrict__ cand) {
  int e = blockIdx.x * blockDim.x + threadIdx.x;
  if (e >= N) return;
  uint k = key32[e];
  if ((int)(k >> 16) == ctrl->binsel) {
    int p = atomicAdd(&ctrl->ncand, 1);
    if (p < CAND_CAP) cand[p] = ((ull)k << 32) | (uint)e;
  }
}

// Rank candidates by packed (key,idx); threshold = rank r_in element.
__global__ void k_pickT(const ull* __restrict__ cand, Ctrl* ctrl) {
  int nc = ctrl->ncand;
  if (nc > CAND_CAP) nc = CAND_CAP;
  int r = ctrl->r_in;
  for (int o = threadIdx.x; o < nc; o += blockDim.x) {
    ull my = cand[o];
    int cnt = 0;
    for (int i = 0; i < nc; ++i) cnt += (cand[i] < my) ? 1 : 0;
    if (cnt == r) ctrl->Tpack = my;   // exactly one (packs are unique)
  }
}

__device__ __forceinline__ int keptf(uint k, int e, ull T) {
  return ((((ull)k << 32) | (uint)e) > T) ? 1 : 0;
}

// Once-only: per-thread packed (excl-pos<<4)|flags, per-chunk sums, mask output.
__global__ void __launch_bounds__(256) k_scanA(
    const uint* __restrict__ key32, const Ctrl* __restrict__ ctrl,
    int* __restrict__ pw, int* __restrict__ bs, float* __restrict__ mask_out) {
  __shared__ int sh[256];
  int t = threadIdx.x, blk = blockIdx.x;
  ull T = ctrl->Tpack;
  uint4 k4 = ((const uint4*)key32)[blk * 256 + t];
  int e0 = blk * 1024 + t * 4;
  int f0 = keptf(k4.x, e0, T), f1 = keptf(k4.y, e0 + 1, T);
  int f2 = keptf(k4.z, e0 + 2, T), f3 = keptf(k4.w, e0 + 3, T);
  int c = f0 + f1 + f2 + f3;
  sh[t] = c;
  __syncthreads();
  for (int off = 1; off < 256; off <<= 1) {
    int v = sh[t];
    int a = (t >= off) ? sh[t - off] : 0;
    __syncthreads();
    sh[t] = v + a;
    __syncthreads();
  }
  int excl = sh[t] - c;
  pw[blk * 256 + t] = (excl << 4) | f0 | (f1 << 1) | (f2 << 2) | (f3 << 3);
  ((float4*)mask_out)[blk * 256 + t] =
      make_float4((float)f0, (float)f1, (float)f2, (float)f3);
  if (t == 255) bs[blk] = sh[255];
}

__global__ void k_scanB(int* bs, int nb) {
  __shared__ int sh[256];
  int t = threadIdx.x;
  int v = (t < nb) ? bs[t] : 0;
  sh[t] = v;
  __syncthreads();
  for (int off = 1; off < 256; off <<= 1) {
    int x = sh[t];
    int a = (t >= off) ? sh[t - off] : 0;
    __syncthreads();
    sh[t] = x + a;
    __syncthreads();
  }
  if (t < nb) bs[t] = sh[t] - v;
}

// Batch-looped wave-autonomous compaction. Each block owns one 1024-chunk and
// iterates 8 batches, reusing pw/shfl/bs setup; 1-deep register pipeline hides
// the next batch's loads under the current batch's LDS drain. No barriers.
// grid = (chunk, batch_group).
__global__ void __launch_bounds__(256) k_compact(
    const int* __restrict__ pw, const int* __restrict__ bs,
    const int* __restrict__ ei, const float* __restrict__ attr,
    ll E, int N, int Kkeep, ll BK, int BPG, float* __restrict__ out) {
  __shared__ float lds[4][3][264];   // [wave][row][slot], 16B-aligned rows
  int t = threadIdx.x;
  int w = t >> 6;       // wave id
  int l = t & 63;       // lane
  int blk = blockIdx.x;
  int b0 = blockIdx.y * BPG;
  int q = blk * 256 + t;            // pw slot; elems 4q..4q+3
  int wv = pw[q];
  int flags = wv & 15;
  int excl = wv >> 4;               // kept-count before elem 4q within 1024-chunk
  int subbase = __shfl(excl, 0);    // wave's sub-chunk base within chunk
  int wlast = __shfl(wv, 63);
  int cnt = (wlast >> 4) + __popc(wlast & 15) - subbase;   // kept in sub-chunk
  int poff = excl - subbase;        // position within wave's compacted run
  ll obase = (ll)bs[blk] + subbase; // batch-independent part of output offset
  float* L0 = lds[w][0];
  float* L1 = lds[w][1];
  float* L2 = lds[w][2];

  // prologue: load batch b0
  ll cb = (ll)b0 * N;
  i4 d0 = *((const i4*)(ei + cb) + q);
  i4 d1 = *((const i4*)(ei + E + cb) + q);
  f4 d2 = *((const f4*)(attr + cb) + q);

  for (int bi = 0; bi < BPG; ++bi) {
    int b = b0 + bi;
    ll ob = (ll)b * Kkeep + obase;
    int al = (int)(ob & 3);
    int p = poff + al;              // stage shifted to output 16B phase
    if (flags & 1) { L0[p] = (float)d0.x; L1[p] = (float)d1.x; L2[p] = d2.x; p++; }
    if (flags & 2) { L0[p] = (float)d0.y; L1[p] = (float)d1.y; L2[p] = d2.y; p++; }
    if (flags & 4) { L0[p] = (float)d0.z; L1[p] = (float)d1.z; L2[p] = d2.z; p++; }
    if (flags & 8) { L0[p] = (float)d0.w; L1[p] = (float)d1.w; L2[p] = d2.w; }
    // issue next batch's loads (independent; hide under drain)
    i4 n0, n1; f4 n2;
    if (bi + 1 < BPG) {
      ll cb2 = (ll)(b + 1) * N;
      n0 = *((const i4*)(ei + cb2) + q);
      n1 = *((const i4*)(ei + E + cb2) + q);
      n2 = *((const f4*)(attr + cb2) + q);
    }
    // drain (same-wave LDS program order; no barrier needed)
    int lo = al, hi = al + cnt;     // valid LDS index range (wave-uniform)
    int nslot = (hi + 3) >> 2;
    ll gbase = ob - al;             // 16B-aligned global base
    #pragma unroll
    for (int r = 0; r < 3; ++r) {
      const float* src = lds[w][r];
      float* dst = out + (ll)r * BK + gbase;
      for (int i = l; i < nslot; i += 64) {
        int j0 = 4 * i;
        f4 v = *(const f4*)(src + j0);
        if (j0 >= lo && j0 + 3 < hi) {
          __builtin_nontemporal_store(v, (f4*)(dst + j0));
        } else {
          if (j0 >= lo && j0 < hi)         __builtin_nontemporal_store(v.x, dst + j0);
          if (j0 + 1 >= lo && j0 + 1 < hi) __builtin_nontemporal_store(v.y, dst + j0 + 1);
          if (j0 + 2 >= lo && j0 + 2 < hi) __builtin_nontemporal_store(v.z, dst + j0 + 2);
          if (j0 + 3 >= lo && j0 + 3 < hi) __builtin_nontemporal_store(v.w, dst + j0 + 3);
        }
      }
    }
    d0 = n0; d1 = n1; d2 = n2;
  }
}

extern "C" void kernel_launch(void* const* d_in, const int* in_sizes, int n_in,
                              void* d_out, int out_size, void* d_ws, size_t ws_size,
                              hipStream_t stream) {
  const int* ei = (const int*)d_in[0];
  const float* attr = (const float*)d_in[1];
  const float* wm = (const float*)d_in[3];

  int B = in_sizes[2] - 1;                          // 64
  ll E = (ll)in_sizes[0] / 2;                       // 16777216
  int e_per = (int)(E / B);                         // 262144
  int D = (int)llround(sqrt((double)in_sizes[3]));  // 4096
  int num_rm = (int)((double)e_per * 0.3);          // 78643
  int Kkeep = e_per - num_rm;                       // 183501
  ll BK = (ll)B * Kkeep;
  int nb = (e_per + 1023) / 1024;                   // 256

  char* w = (char*)d_ws;
  size_t off = 0;
  uint* key32 = (uint*)(w + off);  off += (size_t)e_per * 4;
  uint* hist0 = (uint*)(w + off);  off += 256 * 4;
  uint* hist1 = (uint*)(w + off);  off += 256 * 4;
  Ctrl* ctrl = (Ctrl*)(w + off);   off += 64;
  ull* cand = (ull*)(w + off);     off += (size_t)CAND_CAP * 8;
  int* bs = (int*)(w + off);       off += 1024;
  int* pw = (int*)(w + off);       off += (size_t)(e_per / 4) * 4;
  (void)ws_size; (void)n_in; (void)out_size;

  float* out = (float*)d_out;
  float* mask_out = out + 3 * BK;

  int BPG = 8;
  hipMemsetAsync(hist0, 0, 256 * 4 + 256 * 4 + 64, stream);
  k_keys<<<dim3(e_per / 1024), dim3(256), 0, stream>>>(ei, wm, E, D, key32, hist0);
  k_pick0<<<dim3(1), dim3(256), 0, stream>>>(hist0, num_rm - 1, ctrl);
  k_hist1<<<dim3(e_per / 1024), dim3(256), 0, stream>>>(key32, ctrl, hist1);
  k_pick1<<<dim3(1), dim3(256), 0, stream>>>(hist1, ctrl);
  k_cand<<<dim3(nb), dim3(1024), 0, stream>>>(key32, e_per, ctrl, cand);
  k_pickT<<<dim3(1), dim3(1024), 0, stream>>>(cand, ctrl);
  k_scanA<<<dim3(nb), dim3(256), 0, stream>>>(key32, ctrl, pw, bs, mask_out);
  k_scanB<<<dim3(1), dim3(256), 0, stream>>>(bs, nb);
  k_compact<<<dim3(nb, B / BPG), dim3(256), 0, stream>>>(pw, bs, ei, attr,
                                                         E, e_per, Kkeep, BK, BPG, out);
}